// Round 3
// baseline (241.884 us; speedup 1.0000x reference)
//
#include <hip/hip_runtime.h>

#define NEGF (-1e30f)

// Problem constants (from setup_inputs: B=8, T=128, U=64, V=1024)
#define B_   8
#define T_   128
#define U_   64
#define U1_  65
#define V_   1024
#define PAD_ 66                 // padded row stride; diagonal LDS reads land on distinct banks
#define ROWS_ (B_*T_*U1_)       // 66560
#define WS_PER_ (T_*PAD_)       // 8448 floats per batch per array
#define BPB_  ((T_*U1_)/4)      // blocks per batch = 2080 (exact; blocks never straddle batches)

typedef float f32x4 __attribute__((ext_vector_type(4)));

// lane l receives lane l-1's value; lane 0 keeps its own (DPP wave_shr:1).
__device__ __forceinline__ float wave_shr1(float x) {
  return __int_as_float(__builtin_amdgcn_update_dpp(
      __float_as_int(x), __float_as_int(x), 0x138, 0xf, 0xf, 0));
}

// ---------------------------------------------------------------------------
// Fused kernel. Phase 1 (all 16640 blocks): wave-per-row log-softmax, publish
// lp_blank/lp_label with device-scope stores. Phase 2 (last block per batch):
// stage batch into LDS, run the anti-diagonal DP. Phase 3 (last DP block):
// sum the 8 costs.
// ---------------------------------------------------------------------------
__global__ __launch_bounds__(256) void rnnt_fused(
    const float* __restrict__ acts, const int* __restrict__ labels,
    const int* __restrict__ act_lens, const int* __restrict__ label_lens,
    float* __restrict__ lpb, float* __restrict__ lpl,
    float* __restrict__ costs, int* __restrict__ bcnt, int* __restrict__ done,
    float* __restrict__ out) {
  __shared__ float lpb_s[WS_PER_];
  __shared__ float lpl_s[WS_PER_];
  __shared__ float alpha0_s[T_];
  __shared__ int   isdp_s;

  const int lane = threadIdx.x & 63;
  const int wv   = threadIdx.x >> 6;
  const int row  = blockIdx.x * 4 + wv;
  const int b    = row / (T_ * U1_);
  const int rem  = row - b * (T_ * U1_);
  const int t    = rem / U1_;
  const int u    = rem - t * U1_;
  const float* __restrict__ p = acts + (size_t)row * V_;

  // hoisted label-path loads (lane 0 only); overlap with row load + reductions
  int ll_ = 0; float labv = 0.0f;
  if (lane == 0 && u < U_) {
    ll_  = label_lens[b];
    labv = p[labels[b * U_ + u]];                  // in [1, V)
  }

  // streamed once, no reuse -> nontemporal
  f32x4 v0 = __builtin_nontemporal_load((const f32x4*)(p +   0 + lane * 4));
  f32x4 v1 = __builtin_nontemporal_load((const f32x4*)(p + 256 + lane * 4));
  f32x4 v2 = __builtin_nontemporal_load((const f32x4*)(p + 512 + lane * 4));
  f32x4 v3 = __builtin_nontemporal_load((const f32x4*)(p + 768 + lane * 4));

  float m = fmaxf(fmaxf(fmaxf(v0.x, v0.y), fmaxf(v0.z, v0.w)),
            fmaxf(fmaxf(fmaxf(v1.x, v1.y), fmaxf(v1.z, v1.w)),
            fmaxf(fmaxf(fmaxf(v2.x, v2.y), fmaxf(v2.z, v2.w)),
                  fmaxf(fmaxf(v3.x, v3.y), fmaxf(v3.z, v3.w)))));
  #pragma unroll
  for (int o = 32; o; o >>= 1) m = fmaxf(m, __shfl_xor(m, o, 64));

  float s = __expf(v0.x - m) + __expf(v0.y - m) + __expf(v0.z - m) + __expf(v0.w - m)
          + __expf(v1.x - m) + __expf(v1.y - m) + __expf(v1.z - m) + __expf(v1.w - m)
          + __expf(v2.x - m) + __expf(v2.y - m) + __expf(v2.z - m) + __expf(v2.w - m)
          + __expf(v3.x - m) + __expf(v3.y - m) + __expf(v3.z - m) + __expf(v3.w - m);
  #pragma unroll
  for (int o = 32; o; o >>= 1) s += __shfl_xor(s, o, 64);

  float lse = m + __logf(s);                       // s >= 1

  if (lane == 0) {
    size_t base = ((size_t)b * T_ + t) * PAD_;
    // device-scope (sc1) relaxed stores: visible at the coherent point once
    // vmcnt drains -- avoids a heavy release fence in every block
    __hip_atomic_store(&lpb[base + u], v0.x - lse, __ATOMIC_RELAXED, __HIP_MEMORY_SCOPE_AGENT);
    if (u < U_) {
      float val = (u < ll_) ? (labv - lse) : NEGF;
      __hip_atomic_store(&lpl[base + u], val, __ATOMIC_RELAXED, __HIP_MEMORY_SCOPE_AGENT);
    }
  }

  __syncthreads();                                 // drains each wave's vmcnt before barrier
  if (threadIdx.x == 0) {
    asm volatile("s_waitcnt vmcnt(0)" ::: "memory");
    int old = __hip_atomic_fetch_add(&bcnt[b], 1, __ATOMIC_RELAXED, __HIP_MEMORY_SCOPE_AGENT);
    isdp_s = (old == BPB_ - 1) ? 1 : 0;
  }
  __syncthreads();
  if (!isdp_s) return;

  // ---- Phase 2: this is the last block of batch b -> run the DP ----
  __threadfence();                                 // acquire: invalidate stale cache lines

  {  // stage batch b (float4 flat copy; batch base 16B aligned)
    const f32x4* s1 = (const f32x4*)(lpb + (size_t)b * WS_PER_);
    const f32x4* s2 = (const f32x4*)(lpl + (size_t)b * WS_PER_);
    f32x4* d1 = (f32x4*)lpb_s;
    f32x4* d2 = (f32x4*)lpl_s;
    #pragma unroll
    for (int k = 0; k < 9; ++k) {                  // 9*256 >= 2112
      int i = k * 256 + (int)threadIdx.x;
      if (i < WS_PER_ / 4) { d1[i] = s1[i]; d2[i] = s2[i]; }
    }
  }
  __syncthreads();
  if (threadIdx.x >= 64) return;

  const int l  = threadIdx.x;
  const int tl = act_lens[b] - 1;
  const int ll = label_lens[b];

  // alpha[t][0] = sum_{j<t} lpb[j][0]  (exclusive prefix over T=128, two chunks)
  float x0 = lpb_s[l * PAD_];
  float x1 = lpb_s[(l + 64) * PAD_];
  float s0 = x0;
  #pragma unroll
  for (int o = 1; o < 64; o <<= 1) { float tmp = __shfl_up(s0, o, 64); if (l >= o) s0 += tmp; }
  float tot0 = __shfl(s0, 63, 64);
  float s1v = x1;
  #pragma unroll
  for (int o = 1; o < 64; o <<= 1) { float tmp = __shfl_up(s1v, o, 64); if (l >= o) s1v += tmp; }
  alpha0_s[l]      = s0 - x0;
  alpha0_s[l + 64] = tot0 + s1v - x1;

  // diagonal sweep: at diagonal d, lane l computes cell (t = d-u, u = l+1)
  const int u2 = l + 1;
  float a    = NEGF;
  float fin  = 0.0f;
  bool  have = false;

  int   tc1 = min(max(1 - u2, 0), T_ - 1);
  int   tm1 = max(tc1 - 1, 0);
  float pb  = lpb_s[tm1 * PAD_ + u2];
  float pl  = lpl_s[tc1 * PAD_ + (u2 - 1)];
  float pa0 = alpha0_s[tc1];

  for (int d = 1; d <= T_ - 1 + U_; ++d) {
    // prefetch next diagonal's operands (induction-only addresses)
    int   tcn = min(max(d + 1 - u2, 0), T_ - 1);
    int   tmn = max(tcn - 1, 0);
    float nb  = lpb_s[tmn * PAD_ + u2];
    float nl  = lpl_s[tcn * PAD_ + (u2 - 1)];
    float na0 = alpha0_s[tcn];

    int  t2    = d - u2;
    bool valid = (t2 >= 0) && (t2 < T_);
    float left = wave_shr1(a);                     // alpha[t][u-1] from lane l-1
    if (l == 0) left = pa0;                        // u-1 == 0 column
    float blank = (t2 >= 1 && t2 < T_) ? (a + pb) : NEGF;
    float label = left + pl;
    float mm = fmaxf(blank, label);
    float dd = fminf(blank, label) - mm;           // <= 0; exp underflows safely
    float anew = mm + __logf(1.0f + __expf(dd));
    a = valid ? anew : NEGF;
    if (valid && t2 == tl && u2 == ll) { fin = a; have = true; }

    pb = nb; pl = nl; pa0 = na0;
  }
  if (have)
    __hip_atomic_store(&costs[b], -(fin + lpb_s[tl * PAD_ + ll]),
                       __ATOMIC_RELAXED, __HIP_MEMORY_SCOPE_AGENT);
  if (l == 0 && ll == 0)
    __hip_atomic_store(&costs[b], -(alpha0_s[tl] + lpb_s[tl * PAD_]),
                       __ATOMIC_RELAXED, __HIP_MEMORY_SCOPE_AGENT);

  // ---- Phase 3: last DP block sums the 8 costs (deterministic order) ----
  asm volatile("s_waitcnt vmcnt(0)" ::: "memory");
  if (l == 0) {
    int o = __hip_atomic_fetch_add(done, 1, __ATOMIC_RELAXED, __HIP_MEMORY_SCOPE_AGENT);
    if (o == B_ - 1) {
      __threadfence();
      float ssum = 0.0f;
      #pragma unroll
      for (int i = 0; i < B_; ++i)
        ssum += __hip_atomic_load(&costs[i], __ATOMIC_RELAXED, __HIP_MEMORY_SCOPE_AGENT);
      out[0] = ssum;
    }
  }
}

extern "C" void kernel_launch(void* const* d_in, const int* in_sizes, int n_in,
                              void* d_out, int out_size, void* d_ws, size_t ws_size,
                              hipStream_t stream) {
  const float* acts       = (const float*)d_in[0];
  const int*   labels     = (const int*)d_in[1];
  const int*   act_lens   = (const int*)d_in[2];
  const int*   label_lens = (const int*)d_in[3];

  float* lpb   = (float*)d_ws;                       // B*T*PAD floats
  float* lpl   = lpb + (size_t)B_ * WS_PER_;         // B*T*PAD floats
  float* costs = lpl + (size_t)B_ * WS_PER_;         // B floats
  int*   bcnt  = (int*)(costs + B_);                 // B ints
  int*   done  = bcnt + B_;                          // 1 int

  hipMemsetAsync(bcnt, 0, (B_ + 1) * sizeof(int), stream);   // graph-capturable
  rnnt_fused<<<ROWS_ / 4, 256, 0, stream>>>(acts, labels, act_lens, label_lens,
                                            lpb, lpl, costs, bcnt, done,
                                            (float*)d_out);
}

// Round 4
// 87.263 us; speedup vs baseline: 2.7719x; 2.7719x over previous
//
#include <hip/hip_runtime.h>

#define NEGF (-1e30f)

// Problem constants (from setup_inputs: B=8, T=128, U=64, V=1024)
#define B_   8
#define T_   128
#define U_   64
#define U1_  65
#define V_   1024
#define PAD_ 66                 // padded row stride for lpb/lpl
#define ROWS_ (B_*T_*U1_)       // 66560
#define WS_PER_ (T_*PAD_)       // 8448 floats per batch per array
#define RPW_  16                // rows per wave in k1
#define K1_BLOCKS (ROWS_/(4*RPW_))   // 1040 blocks * 4 waves * 16 rows = 66560

typedef float f32x4 __attribute__((ext_vector_type(4)));

// lane l receives lane l-1's value; lane 0 keeps its own (DPP wave_shr:1).
__device__ __forceinline__ float wave_shr1(float x) {
  return __int_as_float(__builtin_amdgcn_update_dpp(
      __float_as_int(x), __float_as_int(x), 0x138, 0xf, 0xf, 0));
}

// ---------------------------------------------------------------------------
// K1: software-pipelined log-softmax. Each wave owns 16 consecutive rows;
//     row i+1's loads (incl. the label gather) are issued before row i's
//     reduction, so memory stays in flight during the serial shuffle chain.
// ---------------------------------------------------------------------------
__global__ __launch_bounds__(256) void k1_logsoftmax(
    const float* __restrict__ acts, const int* __restrict__ labels,
    const int* __restrict__ label_lens,
    float* __restrict__ lpb, float* __restrict__ lpl, int* __restrict__ cnt) {
  const int lane = threadIdx.x & 63;
  const int wid  = blockIdx.x * 4 + (threadIdx.x >> 6);
  if (wid == 0 && lane == 0) *cnt = 0;             // k2's completion counter

  int row = wid * RPW_;
  int cb  = row / (T_ * U1_);
  int rem = row - cb * (T_ * U1_);
  int ct  = rem / U1_;
  int cu  = rem - ct * U1_;
  const float* p = acts + (size_t)row * V_;

  // prologue: load row 0 of this wave's strip
  f32x4 a0 = *(const f32x4*)(p +   0 + lane * 4);
  f32x4 a1 = *(const f32x4*)(p + 256 + lane * 4);
  f32x4 a2 = *(const f32x4*)(p + 512 + lane * 4);
  f32x4 a3 = *(const f32x4*)(p + 768 + lane * 4);
  float labA = 0.0f; int llA = 0;
  if (lane == 0 && cu < U_) { llA = label_lens[cb]; labA = p[labels[cb * U_ + cu]]; }

  #pragma unroll 1
  for (int i = 0; i < RPW_; ++i) {
    const bool hn = (i < RPW_ - 1);
    // next-row indices
    int nb2 = cb, nt2 = ct, nu2 = cu + 1;
    if (nu2 == U1_) { nu2 = 0; if (++nt2 == T_) { nt2 = 0; ++nb2; } }

    // issue next row's loads (independent of current row's compute)
    f32x4 b0, b1, b2, b3; float labB = 0.0f; int llB = 0;
    if (hn) {
      const float* q = p + V_;
      b0 = *(const f32x4*)(q +   0 + lane * 4);
      b1 = *(const f32x4*)(q + 256 + lane * 4);
      b2 = *(const f32x4*)(q + 512 + lane * 4);
      b3 = *(const f32x4*)(q + 768 + lane * 4);
      if (lane == 0 && nu2 < U_) { llB = label_lens[nb2]; labB = q[labels[nb2 * U_ + nu2]]; }
    }

    // reduce current row
    float m = fmaxf(fmaxf(fmaxf(a0.x, a0.y), fmaxf(a0.z, a0.w)),
              fmaxf(fmaxf(fmaxf(a1.x, a1.y), fmaxf(a1.z, a1.w)),
              fmaxf(fmaxf(fmaxf(a2.x, a2.y), fmaxf(a2.z, a2.w)),
                    fmaxf(fmaxf(a3.x, a3.y), fmaxf(a3.z, a3.w)))));
    #pragma unroll
    for (int o = 32; o; o >>= 1) m = fmaxf(m, __shfl_xor(m, o, 64));

    float s = __expf(a0.x - m) + __expf(a0.y - m) + __expf(a0.z - m) + __expf(a0.w - m)
            + __expf(a1.x - m) + __expf(a1.y - m) + __expf(a1.z - m) + __expf(a1.w - m)
            + __expf(a2.x - m) + __expf(a2.y - m) + __expf(a2.z - m) + __expf(a2.w - m)
            + __expf(a3.x - m) + __expf(a3.y - m) + __expf(a3.z - m) + __expf(a3.w - m);
    #pragma unroll
    for (int o = 32; o; o >>= 1) s += __shfl_xor(s, o, 64);

    float lse = m + __logf(s);                     // s >= 1

    if (lane == 0) {
      int base = (cb * T_ + ct) * PAD_;
      lpb[base + cu] = a0.x - lse;                 // element 0 lives in lane 0's a0.x
      if (cu < U_) lpl[base + cu] = (cu < llA) ? (labA - lse) : NEGF;
    }

    // rotate pipeline
    if (hn) {
      a0 = b0; a1 = b1; a2 = b2; a3 = b3; labA = labB; llA = llB;
      cb = nb2; ct = nt2; cu = nu2; p += V_;
    }
  }
}

// ---------------------------------------------------------------------------
// K2: per-batch alpha lattice via anti-diagonals (unchanged from R2).
//     256 threads stage LDS; wave 0 runs the DP with DPP shift + prefetched
//     operands. Last block also writes the final sum.
// ---------------------------------------------------------------------------
__global__ __launch_bounds__(256) void k2_alpha(
    const float* __restrict__ lpb, const float* __restrict__ lpl,
    const int* __restrict__ act_lens, const int* __restrict__ label_lens,
    float* __restrict__ costs, int* __restrict__ cnt, float* __restrict__ out) {
  __shared__ float lpb_s[WS_PER_];
  __shared__ float lpl_s[WS_PER_];
  __shared__ float alpha0_s[T_];
  const int b = blockIdx.x;

  {  // flat float4 copy (WS_PER_ multiple of 4; batch base is 16B aligned)
    const f32x4* s1 = (const f32x4*)(lpb + (size_t)b * WS_PER_);
    const f32x4* s2 = (const f32x4*)(lpl + (size_t)b * WS_PER_);
    f32x4* d1 = (f32x4*)lpb_s;
    f32x4* d2 = (f32x4*)lpl_s;
    #pragma unroll
    for (int k = 0; k < 9; ++k) {                  // 9*256 >= 2112
      int i = k * 256 + (int)threadIdx.x;
      if (i < WS_PER_ / 4) { d1[i] = s1[i]; d2[i] = s2[i]; }
    }
  }
  __syncthreads();
  if (threadIdx.x >= 64) return;

  const int l  = threadIdx.x;
  const int tl = act_lens[b] - 1;
  const int ll = label_lens[b];

  // alpha[t][0] = sum_{j<t} lpb[j][0]  (exclusive prefix over T=128, two chunks)
  float x0 = lpb_s[l * PAD_];
  float x1 = lpb_s[(l + 64) * PAD_];
  float s0 = x0;
  #pragma unroll
  for (int o = 1; o < 64; o <<= 1) { float tmp = __shfl_up(s0, o, 64); if (l >= o) s0 += tmp; }
  float tot0 = __shfl(s0, 63, 64);
  float s1v = x1;
  #pragma unroll
  for (int o = 1; o < 64; o <<= 1) { float tmp = __shfl_up(s1v, o, 64); if (l >= o) s1v += tmp; }
  alpha0_s[l]      = s0 - x0;
  alpha0_s[l + 64] = tot0 + s1v - x1;

  // diagonal sweep: at diagonal d, lane l computes cell (t = d-u, u = l+1)
  const int u = l + 1;
  float a    = NEGF;
  float fin  = 0.0f;
  bool  have = false;

  int   tc1 = min(max(1 - u, 0), T_ - 1);
  int   tm1 = max(tc1 - 1, 0);
  float pb  = lpb_s[tm1 * PAD_ + u];
  float pl  = lpl_s[tc1 * PAD_ + (u - 1)];
  float pa0 = alpha0_s[tc1];

  for (int d = 1; d <= T_ - 1 + U_; ++d) {
    int   tcn = min(max(d + 1 - u, 0), T_ - 1);
    int   tmn = max(tcn - 1, 0);
    float nb  = lpb_s[tmn * PAD_ + u];
    float nl  = lpl_s[tcn * PAD_ + (u - 1)];
    float na0 = alpha0_s[tcn];

    int  t     = d - u;
    bool valid = (t >= 0) && (t < T_);
    float left = wave_shr1(a);                     // alpha[t][u-1] from lane l-1
    if (l == 0) left = pa0;                        // u-1 == 0 column
    float blank = (t >= 1 && t < T_) ? (a + pb) : NEGF;
    float label = left + pl;
    float mm = fmaxf(blank, label);
    float dd = fminf(blank, label) - mm;           // <= 0; exp underflows safely
    float anew = mm + __logf(1.0f + __expf(dd));
    a = valid ? anew : NEGF;
    if (valid && t == tl && u == ll) { fin = a; have = true; }

    pb = nb; pl = nl; pa0 = na0;
  }
  if (have)              costs[b] = -(fin + lpb_s[tl * PAD_ + ll]);
  if (l == 0 && ll == 0) costs[b] = -(alpha0_s[tl] + lpb_s[tl * PAD_]);

  // last block to arrive sums the 8 costs (deterministic: single writer)
  __threadfence();
  if (l == 0) {
    int old = atomicAdd(cnt, 1);
    if (old == B_ - 1) {
      __threadfence();
      volatile const float* vc = costs;
      float s = 0.0f;
      #pragma unroll
      for (int i = 0; i < B_; ++i) s += vc[i];
      out[0] = s;
    }
  }
}

extern "C" void kernel_launch(void* const* d_in, const int* in_sizes, int n_in,
                              void* d_out, int out_size, void* d_ws, size_t ws_size,
                              hipStream_t stream) {
  const float* acts       = (const float*)d_in[0];
  const int*   labels     = (const int*)d_in[1];
  const int*   act_lens   = (const int*)d_in[2];
  const int*   label_lens = (const int*)d_in[3];

  float* lpb   = (float*)d_ws;                       // B*T*PAD floats
  float* lpl   = lpb + (size_t)B_ * WS_PER_;         // B*T*PAD floats
  float* costs = lpl + (size_t)B_ * WS_PER_;         // B floats
  int*   cnt   = (int*)(costs + B_);                 // 1 int

  k1_logsoftmax<<<K1_BLOCKS, 256, 0, stream>>>(acts, labels, label_lens, lpb, lpl, cnt);
  k2_alpha<<<B_, 256, 0, stream>>>(lpb, lpl, act_lens, label_lens, costs, cnt, (float*)d_out);
}